// Round 12
// baseline (877.363 us; speedup 1.0000x reference)
//
#include <hip/hip_runtime.h>
#include <hip/hip_bf16.h>
#include <cmath>

#define DEVFN __device__ __forceinline__

typedef __attribute__((ext_vector_type(8))) short short8;
typedef __attribute__((ext_vector_type(4))) float f32x4;

constexpr int C_DIM   = 1024;
constexpr int E_NUM   = 8;
constexpr int DFF_DIM = 4096;
constexpr int NTOK    = 8192;       // B*T
constexpr int PAD     = 256;        // expert segment alignment
constexpr int MAXROWS = NTOK * 2 + E_NUM * PAD;  // 18432

DEVFN unsigned short f2bf(float f) {
    __hip_bfloat16 h = __float2bfloat16(f);
    return __builtin_bit_cast(unsigned short, h);
}
DEVFN float bf2f(unsigned short u) {
    return __bfloat162float(__builtin_bit_cast(__hip_bfloat16, u));
}
DEVFN void gload_lds16(const void* g, void* lds) {
    __builtin_amdgcn_global_load_lds(
        (const __attribute__((address_space(1))) unsigned int*)g,
        (__attribute__((address_space(3))) unsigned int*)lds, 16, 0, 0);
}

// meta layout (ints): [0..7] counts, [8..15] cursor, [16..24] offs (offs[8]=padTotal)

// init: zero meta + rowtok, and build wT[o][c] (o<8 gate, o>=8 noise).
__global__ void init_kernel(int* meta, int* rowtok,
                            const float* __restrict__ wg, const float* __restrict__ wn,
                            float* __restrict__ wT) {
    int gid = blockIdx.x * 256 + threadIdx.x;
    if (gid < 64) meta[gid] = 0;
    if (gid < MAXROWS) rowtok[gid] = 0;
    if (gid < 16 * C_DIM) {
        int o = gid >> 10, c = gid & 1023;
        wT[gid] = (o < 8) ? wg[c * 8 + o] : wn[c * 8 + (o - 8)];
    }
}

// Router: 32 tokens/block, 8 threads/token, wT staged in LDS (64KB).
__global__ __launch_bounds__(256) void router_kernel(
    const float* __restrict__ x, const float* __restrict__ noise,
    const float* __restrict__ wT, const float* __restrict__ bg,
    const float* __restrict__ bn, int* meta, int2* tok_e, float2* tok_w) {
    extern __shared__ float swT[];  // 16*1024 floats = 64KB
    int tid = threadIdx.x;
#pragma unroll
    for (int j = 0; j < 16; j++) {
        int idx = (j * 256 + tid) * 4;
        *(float4*)&swT[idx] = *(const float4*)&wT[idx];
    }
    __syncthreads();

    int tt = tid >> 3, sub = tid & 7;
    int tok = blockIdx.x * 32 + tt;
    const float* xr = x + (size_t)tok * C_DIM;

    double acc[16];
#pragma unroll
    for (int o = 0; o < 16; o++) acc[o] = 0.0;

#pragma unroll 4
    for (int i = 0; i < 32; i++) {
        int c = i * 32 + sub * 4;
        float4 xv = *(const float4*)(xr + c);
#pragma unroll
        for (int o = 0; o < 16; o++) {
            float4 wv = *(const float4*)(&swT[o * C_DIM + c]);
            acc[o] += (double)xv.x * (double)wv.x;
            acc[o] += (double)xv.y * (double)wv.y;
            acc[o] += (double)xv.z * (double)wv.z;
            acc[o] += (double)xv.w * (double)wv.w;
        }
    }
#pragma unroll
    for (int s = 1; s <= 4; s <<= 1) {
#pragma unroll
        for (int o = 0; o < 16; o++) acc[o] += __shfl_xor(acc[o], s, 64);
    }
    if (sub == 0) {
        double logit[8];
#pragma unroll
        for (int e = 0; e < 8; e++) {
            double cl = acc[e] + (double)bg[e];
            double nl = acc[8 + e] + (double)bn[e];
            double sp = (nl > 30.0) ? nl : log1p(exp(nl));
            logit[e] = cl + (double)noise[(size_t)tok * 8 + e] * sp;
        }
        int i1 = -1, i2 = -1;
        double v1 = -1e300, v2 = -1e300;
#pragma unroll
        for (int e = 0; e < 8; e++) {
            double v = logit[e];
            if (v > v1) { v2 = v1; i2 = i1; v1 = v; i1 = e; }
            else if (v > v2) { v2 = v; i2 = e; }
        }
        double d = exp(v2 - v1);
        tok_e[tok] = make_int2(i1, i2);
        tok_w[tok] = make_float2((float)(1.0 / (1.0 + d)), (float)(d / (1.0 + d)));
        atomicAdd(&meta[i1], 1);
        atomicAdd(&meta[i2], 1);
    }
}

__global__ void offsets_kernel(int* meta) {
    if (threadIdx.x == 0 && blockIdx.x == 0) {
        int off = 0;
        for (int e = 0; e < 8; e++) {
            meta[16 + e] = off;
            off += (meta[e] + PAD - 1) / PAD * PAD;
            meta[8 + e] = 0;  // cursor
        }
        meta[24] = off;  // padTotal
    }
}

// Wave-aggregated slot assignment (atomic order doesn't affect any FP result).
__global__ void assign_kernel(int* meta, const int2* tok_e,
                              int2* tok_pos, int* rowtok) {
    int t = blockIdx.x * 256 + threadIdx.x;
    int lane = threadIdx.x & 63;
    int2 e = tok_e[t];
    int sel[2] = {e.x, e.y};
    int pos[2];
#pragma unroll
    for (int s = 0; s < 2; s++) {
        int p = 0;
#pragma unroll
        for (int ex = 0; ex < 8; ex++) {
            unsigned long long m = __ballot(sel[s] == ex);
            if (m) {
                int leader = __ffsll((unsigned long long)m) - 1;
                int base = 0;
                if (lane == leader) base = atomicAdd(&meta[8 + ex], (int)__popcll(m));
                base = __shfl(base, leader, 64);
                if (sel[s] == ex)
                    p = meta[16 + ex] + base + (int)__popcll(m & ((1ull << lane) - 1ull));
            }
        }
        pos[s] = p;
        rowtok[p] = t;
    }
    tok_pos[t] = make_int2(pos[0], pos[1]);
}

// Transpose body: [R][S] fp32 tile (r0,s0) -> [S][R] bf16, 64x64, vectorized.
DEVFN void transpose_body(const float* __restrict__ ine, unsigned short* __restrict__ oute,
                          int R, int S, int r0, int s0, float (*tile)[68]) {
    int tid = threadIdx.x;
    int rr = tid >> 2, cs = (tid & 3) * 16;
    const float4* src = (const float4*)(ine + (size_t)(r0 + rr) * S + s0 + cs);
#pragma unroll
    for (int q = 0; q < 4; q++) *(float4*)&tile[rr][cs + q * 4] = src[q];
    __syncthreads();
    int ss = tid >> 2, rs = (tid & 3) * 16;
    ushort4 o[4];
#pragma unroll
    for (int q = 0; q < 4; q++) {
        ushort4 v;
        v.x = f2bf(tile[rs + q * 4 + 0][ss]);
        v.y = f2bf(tile[rs + q * 4 + 1][ss]);
        v.z = f2bf(tile[rs + q * 4 + 2][ss]);
        v.w = f2bf(tile[rs + q * 4 + 3][ss]);
        o[q] = v;
    }
    ushort4* dst = (ushort4*)(oute + (size_t)(s0 + ss) * R + r0 + rs);
#pragma unroll
    for (int q = 0; q < 4; q++) dst[q] = o[q];
}

// prep: fused {transpose w1, transpose w2, gather x} by block range.
constexpr int NB_T1 = (DFF_DIM / 64) * (C_DIM / 64) * E_NUM;  // 8192
constexpr int NB_T2 = (C_DIM / 64) * (DFF_DIM / 64) * E_NUM;  // 8192
__global__ __launch_bounds__(256) void prep_kernel(
    const float* __restrict__ w1, unsigned short* __restrict__ w1b,
    const float* __restrict__ w2, unsigned short* __restrict__ w2b,
    const float* __restrict__ x, const int* __restrict__ rowtok,
    unsigned short* __restrict__ Xg) {
    __shared__ float tile[64][68];
    int b = blockIdx.x;
    if (b < NB_T1) {
        int bx = b & 63, by = (b >> 6) & 15, bz = b >> 10;
        transpose_body(w1 + (size_t)bz * C_DIM * DFF_DIM,
                       w1b + (size_t)bz * C_DIM * DFF_DIM,
                       C_DIM, DFF_DIM, by * 64, bx * 64, tile);
        return;
    }
    b -= NB_T1;
    if (b < NB_T2) {
        int bx = b & 15, by = (b >> 4) & 63, bz = b >> 10;
        transpose_body(w2 + (size_t)bz * C_DIM * DFF_DIM,
                       w2b + (size_t)bz * C_DIM * DFF_DIM,
                       DFF_DIM, C_DIM, by * 64, bx * 64, tile);
        return;
    }
    b -= NB_T2;
    // gather row b
    int tok = rowtok[b];
    const float4* src = (const float4*)(x + (size_t)tok * C_DIM);
    ushort4* dst = (ushort4*)(Xg + (size_t)b * C_DIM);
    int i = threadIdx.x;
    float4 v = src[i];
    ushort4 o;
    o.x = f2bf(v.x); o.y = f2bf(v.y); o.z = f2bf(v.z); o.w = f2bf(v.w);
    dst[i] = o;
}

// ---------------------------------------------------------------------------
// R12 GEMM: 256x256 tile, 256 thr = 4 waves (2x2), wave tile 128x128.
// MFMA:ds_read = 128:32 per wave per K-tile (was 64:24) -> LDS pipe no longer
// co-critical with MFMA. 1 wave/SIMD (acc 256 VGPR + frags ~84; <450 no-spill
// per m08); LDS 128KB (BK=64 dbuf) -> 1 block/CU. Loop = proven R8 single
// region + one vmcnt(0) + one barrier per K-tile; kk-outer frag loads.
// Swizzle: 128B rows, 16B slot s at phys s^(row&7) on gload SOURCE + read.
// MODE 1: relu(acc+bias) -> OutH.  MODE 2: acc + (z==0)*bias -> OutC[z].
// ---------------------------------------------------------------------------
template <int KDIM, int KLEN, int NDIM, int MODE>
__global__ __launch_bounds__(256, 1) void gemm8_kernel(
    const unsigned short* __restrict__ A, const unsigned short* __restrict__ Bt,
    const float* __restrict__ bias, unsigned short* __restrict__ OutH,
    unsigned short* __restrict__ OutC0, unsigned short* __restrict__ OutC1,
    unsigned short* __restrict__ OutC2, unsigned short* __restrict__ OutC3,
    const int* __restrict__ meta) {
    extern __shared__ char ldsraw[];  // 131072 bytes

    int nwg = gridDim.x;
    int orig = blockIdx.x;
    int q = nwg >> 3, r8 = nwg & 7;
    int xcd = orig & 7, idx = orig >> 3;
    int wgid = (xcd < r8 ? xcd * (q + 1) : r8 * (q + 1) + (xcd - r8) * q) + idx;
    constexpr int NCT = NDIM / 256;
    int rowBase = (wgid / NCT) * 256;
    int colBase = (wgid % NCT) * 256;
    if (rowBase >= meta[24]) return;
    int e = 0;
#pragma unroll
    for (int i = 1; i < 8; i++)
        if (rowBase >= meta[16 + i]) e = i;
    int koff = blockIdx.z * KLEN;

    int tid = threadIdx.x;
    int wv = tid >> 6, lane = tid & 63;
    int wr = wv >> 1, wc = wv & 1;  // 2x2 waves; wave output 128x128

    const unsigned short* Ab = A + (size_t)rowBase * KDIM + koff;
    const unsigned short* Bb = Bt + (size_t)e * NDIM * KDIM + (size_t)colBase * KDIM + koff;

    // Staging: chunk j = 32 rows (4KB); row = j*32 + (tid>>3),
    // src slot = (tid&7) ^ (row&7)  [row&7 == (tid>>3)&7].
    int rA = tid >> 3;
    int sSl = ((tid & 7) ^ (rA & 7)) * 8;
    const unsigned short* pA0 = Ab + (size_t)rA * KDIM + sSl;
    const unsigned short* pB0 = Bb + (size_t)rA * KDIM + sSl;

#define STAGEALL(tt) { \
        char* base_ = ldsraw + (((tt) & 1) << 16); \
        size_t kadd_ = (size_t)(tt) * 64; \
        _Pragma("unroll") for (int j_ = 0; j_ < 8; j_++) { \
            gload_lds16(pA0 + (size_t)j_ * 32 * KDIM + kadd_, \
                        base_ + j_ * 4096 + wv * 1024); \
            gload_lds16(pB0 + (size_t)j_ * 32 * KDIM + kadd_, \
                        base_ + 32768 + j_ * 4096 + wv * 1024); \
        } }

    // Fragment bases (swizzled): phys = (kk*4 | (lane>>4)) ^ (lane&7).
    int physk0 = (lane >> 4) ^ (lane & 7);
    int kdel = ((physk0 ^ 4) - physk0) * 16;  // +-64 bytes to kk=1 slot
    const char* aB0k0 = ldsraw + wr * 16384 + (lane & 15) * 128 + physk0 * 16;
    const char* bB0k0 = ldsraw + 32768 + wc * 16384 + (lane & 15) * 128 + physk0 * 16;

    short8 af[8], bf[8];
    f32x4 acc[8][8];
#pragma unroll
    for (int m = 0; m < 8; m++)
#pragma unroll
        for (int n = 0; n < 8; n++) acc[m][n] = f32x4{0.f, 0.f, 0.f, 0.f};

#define SB() __builtin_amdgcn_sched_barrier(0)

    constexpr int T = KLEN / 64;

    STAGEALL(0)
    SB(); asm volatile("s_waitcnt vmcnt(0)" ::: "memory"); SB();
    __builtin_amdgcn_s_barrier(); SB();

#pragma unroll 1
    for (int t = 0; t < T; ++t) {
        if (t + 1 < T) STAGEALL(t + 1)
        const char* ab = aB0k0 + ((t & 1) << 16);
        const char* bb = bB0k0 + ((t & 1) << 16);
#pragma unroll
        for (int kk = 0; kk < 2; kk++) {
            const char* ak = ab + kk * kdel;
            const char* bk = bb + kk * kdel;
#pragma unroll
            for (int m = 0; m < 8; m++) af[m] = *(const short8*)(ak + m * 2048);
#pragma unroll
            for (int n = 0; n < 8; n++) bf[n] = *(const short8*)(bk + n * 2048);
            __builtin_amdgcn_s_setprio(1);
#pragma unroll
            for (int m = 0; m < 8; m++)
#pragma unroll
                for (int n = 0; n < 8; n++)
                    acc[m][n] = __builtin_amdgcn_mfma_f32_16x16x32_bf16(
                        af[m], bf[n], acc[m][n], 0, 0, 0);
            __builtin_amdgcn_s_setprio(0);
        }
        SB();
        asm volatile("s_waitcnt vmcnt(0)" ::: "memory");
        SB();
        __builtin_amdgcn_s_barrier();
        SB();
    }
#undef STAGEALL

    // Unified epilogue: bf16 via LDS repack with rr-XOR swizzle.
    float bv[8];
    bool addBias = (MODE == 1) || (blockIdx.z == 0);
#pragma unroll
    for (int n = 0; n < 8; n++)
        bv[n] = addBias ? bias[(size_t)e * NDIM + colBase + wc * 128 + n * 16 + (lane & 15)]
                        : 0.f;
    unsigned short* OutP = (MODE == 1) ? OutH
                         : (blockIdx.z == 0 ? OutC0 : blockIdx.z == 1 ? OutC1
                         : blockIdx.z == 2 ? OutC2 : OutC3);

    unsigned short* lds16 = (unsigned short*)ldsraw;
#pragma unroll
    for (int m = 0; m < 8; m++) {
#pragma unroll
        for (int n = 0; n < 8; n++) {
#pragma unroll
            for (int j = 0; j < 4; j++) {
                float v = acc[m][n][j] + bv[n];
                if (MODE == 1) v = fmaxf(v, 0.f);
                int rr = wr * 128 + m * 16 + (lane >> 4) * 4 + j;
                int cc = wc * 128 + n * 16 + (lane & 15);
                lds16[rr * 256 + (cc ^ ((rr & 7) << 4))] = f2bf(v);
            }
        }
    }
    __syncthreads();
    {
        int row = tid;  // 256 rows, 512B each
        int xr = (row & 7) << 4;
#pragma unroll
        for (int i = 0; i < 32; i++) {
            int cs = i * 8;
            short8 val = *(const short8*)(lds16 + row * 256 + (cs ^ xr));
            *(short8*)(OutP + (size_t)(rowBase + row) * NDIM + colBase + cs) = val;
        }
    }
}

// out[t] = w0*sum_z cz[p0] + w1*sum_z cz[p1]  (fixed order, deterministic)
__global__ void combine_kernel(const unsigned short* __restrict__ c0,
                               const unsigned short* __restrict__ c1,
                               const unsigned short* __restrict__ c2,
                               const unsigned short* __restrict__ c3,
                               const int2* __restrict__ tok_pos, const float2* __restrict__ tok_w,
                               float* __restrict__ out) {
    int t = blockIdx.x;
    int2 p = tok_pos[t];
    float2 w = tok_w[t];
    int i = threadIdx.x;  // 256 x 4 elems
    size_t o0 = (size_t)p.x * C_DIM, o1 = (size_t)p.y * C_DIM;
    ushort4 a0 = ((const ushort4*)(c0 + o0))[i];
    ushort4 a1 = ((const ushort4*)(c1 + o0))[i];
    ushort4 a2 = ((const ushort4*)(c2 + o0))[i];
    ushort4 a3 = ((const ushort4*)(c3 + o0))[i];
    ushort4 b0 = ((const ushort4*)(c0 + o1))[i];
    ushort4 b1 = ((const ushort4*)(c1 + o1))[i];
    ushort4 b2 = ((const ushort4*)(c2 + o1))[i];
    ushort4 b3 = ((const ushort4*)(c3 + o1))[i];
    float4 r;
    r.x = w.x * (bf2f(a0.x) + bf2f(a1.x) + bf2f(a2.x) + bf2f(a3.x))
        + w.y * (bf2f(b0.x) + bf2f(b1.x) + bf2f(b2.x) + bf2f(b3.x));
    r.y = w.x * (bf2f(a0.y) + bf2f(a1.y) + bf2f(a2.y) + bf2f(a3.y))
        + w.y * (bf2f(b0.y) + bf2f(b1.y) + bf2f(b2.y) + bf2f(b3.y));
    r.z = w.x * (bf2f(a0.z) + bf2f(a1.z) + bf2f(a2.z) + bf2f(a3.z))
        + w.y * (bf2f(b0.z) + bf2f(b1.z) + bf2f(b2.z) + bf2f(b3.z));
    r.w = w.x * (bf2f(a0.w) + bf2f(a1.w) + bf2f(a2.w) + bf2f(a3.w))
        + w.y * (bf2f(b0.w) + bf2f(b1.w) + bf2f(b2.w) + bf2f(b3.w));
    ((float4*)(out + (size_t)t * C_DIM))[i] = r;
}

extern "C" void kernel_launch(void* const* d_in, const int* in_sizes, int n_in,
                              void* d_out, int out_size, void* d_ws, size_t ws_size,
                              hipStream_t stream) {
    (void)in_sizes; (void)n_in; (void)out_size; (void)ws_size;
    const float* x       = (const float*)d_in[0];
    const float* noise   = (const float*)d_in[1];
    const float* w_gate  = (const float*)d_in[2];
    const float* b_gate  = (const float*)d_in[3];
    const float* w_noise = (const float*)d_in[4];
    const float* b_noise = (const float*)d_in[5];
    const float* w1      = (const float*)d_in[6];
    const float* b1      = (const float*)d_in[7];
    const float* w2      = (const float*)d_in[8];
    const float* b2      = (const float*)d_in[9];
    float* out = (float*)d_out;

    char* w = (char*)d_ws;
    size_t off = 0;
    int* meta = (int*)(w + off); off += 256;
    float* wT = (float*)(w + off); off += 16 * C_DIM * 4;
    int2* tok_e = (int2*)(w + off); off += (size_t)NTOK * 8;
    float2* tok_w = (float2*)(w + off); off += (size_t)NTOK * 8;
    int2* tok_pos = (int2*)(w + off); off += (size_t)NTOK * 8;
    int* rowtok = (int*)(w + off); off += (size_t)MAXROWS * 4;
    unsigned short* H = (unsigned short*)(w + off); off += (size_t)MAXROWS * DFF_DIM * 2;
    unsigned short* w2b = (unsigned short*)(w + off); off += (size_t)E_NUM * C_DIM * DFF_DIM * 2;
    unsigned short* c0 = (unsigned short*)(w + off); off += (size_t)MAXROWS * C_DIM * 2;
    unsigned short* Xg = (unsigned short*)(w + off); off += (size_t)MAXROWS * C_DIM * 2;
    unsigned short* w1b = (unsigned short*)(w + off); off += (size_t)E_NUM * DFF_DIM * C_DIM * 2;
    unsigned short* c3 = (unsigned short*)(w + off); off += (size_t)MAXROWS * C_DIM * 2;
    // c1 aliases Xg, c2 aliases w1b (both dead after gemm1; fully rewritten by
    // prep on every call -> replay-safe).
    unsigned short* c1 = Xg;
    unsigned short* c2 = w1b;

    init_kernel<<<(MAXROWS + 255) / 256, 256, 0, stream>>>(meta, rowtok, w_gate, w_noise, wT);

    hipFuncSetAttribute((const void*)router_kernel,
                        hipFuncAttributeMaxDynamicSharedMemorySize, 65536);
    router_kernel<<<NTOK / 32, 256, 65536, stream>>>(x, noise, wT, b_gate, b_noise,
                                                     meta, tok_e, tok_w);
    offsets_kernel<<<1, 64, 0, stream>>>(meta);
    assign_kernel<<<NTOK / 256, 256, 0, stream>>>(meta, tok_e, tok_pos, rowtok);
    prep_kernel<<<NB_T1 + NB_T2 + MAXROWS, 256, 0, stream>>>(w1, w1b, w2, w2b, x, rowtok, Xg);

    hipFuncSetAttribute((const void*)gemm8_kernel<C_DIM, C_DIM, DFF_DIM, 1>,
                        hipFuncAttributeMaxDynamicSharedMemorySize, 131072);
    gemm8_kernel<C_DIM, C_DIM, DFF_DIM, 1>
        <<<dim3((MAXROWS / 256) * (DFF_DIM / 256), 1, 1), 256, 131072, stream>>>(
            Xg, w1b, b1, H, nullptr, nullptr, nullptr, nullptr, meta);

    hipFuncSetAttribute((const void*)gemm8_kernel<DFF_DIM, DFF_DIM / 4, C_DIM, 2>,
                        hipFuncAttributeMaxDynamicSharedMemorySize, 131072);
    gemm8_kernel<DFF_DIM, DFF_DIM / 4, C_DIM, 2>
        <<<dim3((MAXROWS / 256) * (C_DIM / 256), 1, 4), 256, 131072, stream>>>(
            H, w2b, b2, nullptr, c0, c1, c2, c3, meta);

    combine_kernel<<<NTOK, 256, 0, stream>>>(c0, c1, c2, c3, tok_pos, tok_w, out);
}

// Round 13
// 626.339 us; speedup vs baseline: 1.4008x; 1.4008x over previous
//
#include <hip/hip_runtime.h>
#include <hip/hip_bf16.h>
#include <cmath>

#define DEVFN __device__ __forceinline__

typedef __attribute__((ext_vector_type(8))) short short8;
typedef __attribute__((ext_vector_type(4))) float f32x4;

constexpr int C_DIM   = 1024;
constexpr int E_NUM   = 8;
constexpr int DFF_DIM = 4096;
constexpr int NTOK    = 8192;       // B*T
constexpr int PAD     = 256;        // expert segment alignment
constexpr int MAXROWS = NTOK * 2 + E_NUM * PAD;  // 18432

DEVFN unsigned short f2bf(float f) {
    __hip_bfloat16 h = __float2bfloat16(f);
    return __builtin_bit_cast(unsigned short, h);
}
DEVFN float bf2f(unsigned short u) {
    return __bfloat162float(__builtin_bit_cast(__hip_bfloat16, u));
}
DEVFN void gload_lds16(const void* g, void* lds) {
    __builtin_amdgcn_global_load_lds(
        (const __attribute__((address_space(1))) unsigned int*)g,
        (__attribute__((address_space(3))) unsigned int*)lds, 16, 0, 0);
}

// meta layout (ints): [0..7] counts, [8..15] cursor, [16..24] offs (offs[8]=padTotal)

// init: zero meta + rowtok, and build wT[o][c] (o<8 gate, o>=8 noise).
__global__ void init_kernel(int* meta, int* rowtok,
                            const float* __restrict__ wg, const float* __restrict__ wn,
                            float* __restrict__ wT) {
    int gid = blockIdx.x * 256 + threadIdx.x;
    if (gid < 64) meta[gid] = 0;
    if (gid < MAXROWS) rowtok[gid] = 0;
    if (gid < 16 * C_DIM) {
        int o = gid >> 10, c = gid & 1023;
        wT[gid] = (o < 8) ? wg[c * 8 + o] : wn[c * 8 + (o - 8)];
    }
}

// Router: 32 tokens/block, 8 threads/token, wT staged in LDS (64KB).
__global__ __launch_bounds__(256) void router_kernel(
    const float* __restrict__ x, const float* __restrict__ noise,
    const float* __restrict__ wT, const float* __restrict__ bg,
    const float* __restrict__ bn, int* meta, int2* tok_e, float2* tok_w) {
    extern __shared__ float swT[];  // 16*1024 floats = 64KB
    int tid = threadIdx.x;
#pragma unroll
    for (int j = 0; j < 16; j++) {
        int idx = (j * 256 + tid) * 4;
        *(float4*)&swT[idx] = *(const float4*)&wT[idx];
    }
    __syncthreads();

    int tt = tid >> 3, sub = tid & 7;
    int tok = blockIdx.x * 32 + tt;
    const float* xr = x + (size_t)tok * C_DIM;

    double acc[16];
#pragma unroll
    for (int o = 0; o < 16; o++) acc[o] = 0.0;

#pragma unroll 4
    for (int i = 0; i < 32; i++) {
        int c = i * 32 + sub * 4;
        float4 xv = *(const float4*)(xr + c);
#pragma unroll
        for (int o = 0; o < 16; o++) {
            float4 wv = *(const float4*)(&swT[o * C_DIM + c]);
            acc[o] += (double)xv.x * (double)wv.x;
            acc[o] += (double)xv.y * (double)wv.y;
            acc[o] += (double)xv.z * (double)wv.z;
            acc[o] += (double)xv.w * (double)wv.w;
        }
    }
#pragma unroll
    for (int s = 1; s <= 4; s <<= 1) {
#pragma unroll
        for (int o = 0; o < 16; o++) acc[o] += __shfl_xor(acc[o], s, 64);
    }
    if (sub == 0) {
        double logit[8];
#pragma unroll
        for (int e = 0; e < 8; e++) {
            double cl = acc[e] + (double)bg[e];
            double nl = acc[8 + e] + (double)bn[e];
            double sp = (nl > 30.0) ? nl : log1p(exp(nl));
            logit[e] = cl + (double)noise[(size_t)tok * 8 + e] * sp;
        }
        int i1 = -1, i2 = -1;
        double v1 = -1e300, v2 = -1e300;
#pragma unroll
        for (int e = 0; e < 8; e++) {
            double v = logit[e];
            if (v > v1) { v2 = v1; i2 = i1; v1 = v; i1 = e; }
            else if (v > v2) { v2 = v; i2 = e; }
        }
        double d = exp(v2 - v1);
        tok_e[tok] = make_int2(i1, i2);
        tok_w[tok] = make_float2((float)(1.0 / (1.0 + d)), (float)(d / (1.0 + d)));
        atomicAdd(&meta[i1], 1);
        atomicAdd(&meta[i2], 1);
    }
}

__global__ void offsets_kernel(int* meta) {
    if (threadIdx.x == 0 && blockIdx.x == 0) {
        int off = 0;
        for (int e = 0; e < 8; e++) {
            meta[16 + e] = off;
            off += (meta[e] + PAD - 1) / PAD * PAD;
            meta[8 + e] = 0;  // cursor
        }
        meta[24] = off;  // padTotal
    }
}

// Wave-aggregated slot assignment (atomic order doesn't affect any FP result).
__global__ void assign_kernel(int* meta, const int2* tok_e,
                              int2* tok_pos, int* rowtok) {
    int t = blockIdx.x * 256 + threadIdx.x;
    int lane = threadIdx.x & 63;
    int2 e = tok_e[t];
    int sel[2] = {e.x, e.y};
    int pos[2];
#pragma unroll
    for (int s = 0; s < 2; s++) {
        int p = 0;
#pragma unroll
        for (int ex = 0; ex < 8; ex++) {
            unsigned long long m = __ballot(sel[s] == ex);
            if (m) {
                int leader = __ffsll((unsigned long long)m) - 1;
                int base = 0;
                if (lane == leader) base = atomicAdd(&meta[8 + ex], (int)__popcll(m));
                base = __shfl(base, leader, 64);
                if (sel[s] == ex)
                    p = meta[16 + ex] + base + (int)__popcll(m & ((1ull << lane) - 1ull));
            }
        }
        pos[s] = p;
        rowtok[p] = t;
    }
    tok_pos[t] = make_int2(pos[0], pos[1]);
}

// Transpose body: [R][S] fp32 tile (r0,s0) -> [S][R] bf16, 64x64, vectorized.
// Writes as 2x short8 (16B stores).
DEVFN void transpose_body(const float* __restrict__ ine, unsigned short* __restrict__ oute,
                          int R, int S, int r0, int s0, float (*tile)[68]) {
    int tid = threadIdx.x;
    int rr = tid >> 2, cs = (tid & 3) * 16;
    const float4* src = (const float4*)(ine + (size_t)(r0 + rr) * S + s0 + cs);
#pragma unroll
    for (int q = 0; q < 4; q++) *(float4*)&tile[rr][cs + q * 4] = src[q];
    __syncthreads();
    int ss = tid >> 2, rs = (tid & 3) * 16;
    short8 v0, v1;
#pragma unroll
    for (int q = 0; q < 8; q++) v0[q] = (short)f2bf(tile[rs + q][ss]);
#pragma unroll
    for (int q = 0; q < 8; q++) v1[q] = (short)f2bf(tile[rs + 8 + q][ss]);
    unsigned short* dst = oute + (size_t)(s0 + ss) * R + r0 + rs;
    *(short8*)dst = v0;
    *(short8*)(dst + 8) = v1;
}

// prep: fused {transpose w1, transpose w2, convert x->bf16} by block range.
constexpr int NB_T1 = (DFF_DIM / 64) * (C_DIM / 64) * E_NUM;  // 8192
constexpr int NB_T2 = (C_DIM / 64) * (DFF_DIM / 64) * E_NUM;  // 8192
__global__ __launch_bounds__(256) void prep_kernel(
    const float* __restrict__ w1, unsigned short* __restrict__ w1b,
    const float* __restrict__ w2, unsigned short* __restrict__ w2b,
    const float* __restrict__ x, unsigned short* __restrict__ xb) {
    __shared__ float tile[64][68];
    int b = blockIdx.x;
    if (b < NB_T1) {
        int bx = b & 63, by = (b >> 6) & 15, bz = b >> 10;
        transpose_body(w1 + (size_t)bz * C_DIM * DFF_DIM,
                       w1b + (size_t)bz * C_DIM * DFF_DIM,
                       C_DIM, DFF_DIM, by * 64, bx * 64, tile);
        return;
    }
    b -= NB_T1;
    if (b < NB_T2) {
        int bx = b & 15, by = (b >> 4) & 63, bz = b >> 10;
        transpose_body(w2 + (size_t)bz * C_DIM * DFF_DIM,
                       w2b + (size_t)bz * C_DIM * DFF_DIM,
                       DFF_DIM, C_DIM, by * 64, bx * 64, tile);
        return;
    }
    b -= NB_T2;
    // convert token row b: x fp32 -> xb bf16 (token order)
    const float4* src = (const float4*)(x + (size_t)b * C_DIM);
    ushort4* dst = (ushort4*)(xb + (size_t)b * C_DIM);
    int i = threadIdx.x;
    float4 v = src[i];
    ushort4 o;
    o.x = f2bf(v.x); o.y = f2bf(v.y); o.z = f2bf(v.z); o.w = f2bf(v.w);
    dst[i] = o;
}

// ---------------------------------------------------------------------------
// 256x256 GEMM (measured-best R8/R11 structure), 512 thr = 8 waves (2M x 4N),
// BK=64, dbuf x2 (2 x 64KB LDS). Per K-tile: stage(t+1) (8 gload_lds), then
// 24 ds_read + 64 MFMA free-scheduled, ONE vmcnt(0) + ONE s_barrier.
// Swizzle: 128B rows, 16B slot s at phys s^(row&7) on gload SOURCE + read.
// INDIR: A-rows fetched via rowtok indirection from token-ordered xb
// (per-lane global source addr; LDS dest stays linear).
// MODE 1: relu(acc+bias) -> OutH.  MODE 2: acc + (z==0)*bias -> OutC{z}.
// ---------------------------------------------------------------------------
template <int KDIM, int KLEN, int NDIM, int MODE, bool INDIR>
__global__ __launch_bounds__(512, 2) void gemm8_kernel(
    const unsigned short* __restrict__ A, const unsigned short* __restrict__ Bt,
    const float* __restrict__ bias, unsigned short* __restrict__ OutH,
    unsigned short* __restrict__ OutC0, unsigned short* __restrict__ OutC1,
    const int* __restrict__ meta, const int* __restrict__ rowtok) {
    extern __shared__ char ldsraw[];  // 131072 bytes

    int nwg = gridDim.x;
    int orig = blockIdx.x;
    int q = nwg >> 3, r8 = nwg & 7;
    int xcd = orig & 7, idx = orig >> 3;
    int wgid = (xcd < r8 ? xcd * (q + 1) : r8 * (q + 1) + (xcd - r8) * q) + idx;
    constexpr int NCT = NDIM / 256;
    int rowBase = (wgid / NCT) * 256;
    int colBase = (wgid % NCT) * 256;
    if (rowBase >= meta[24]) return;
    int e = 0;
#pragma unroll
    for (int i = 1; i < 8; i++)
        if (rowBase >= meta[16 + i]) e = i;
    int koff = blockIdx.z * KLEN;

    int tid = threadIdx.x;
    int wv = tid >> 6, lane = tid & 63;
    int wr = wv >> 2, wcol = wv & 3;  // 2M x 4N waves; wave output 128x64

    const unsigned short* Bb = Bt + (size_t)e * NDIM * KDIM + (size_t)colBase * KDIM + koff;

    // Staging decode: LDS chunk j (8KB) holds rows rA + j*64; src 16B-slot
    // s = (tid&7) ^ (row&7)  [row&7 == (tid>>3)&7 for all j].
    int rA = tid >> 3;
    int sSl = ((tid & 7) ^ (rA & 7)) * 8;
    const unsigned short* pA[4];
    if constexpr (INDIR) {
#pragma unroll
        for (int j = 0; j < 4; j++) {
            int tok = rowtok[rowBase + rA + j * 64];
            pA[j] = A + (size_t)tok * KDIM + sSl + koff;
        }
    } else {
        const unsigned short* pA0 = A + (size_t)(rowBase + rA) * KDIM + sSl + koff;
#pragma unroll
        for (int j = 0; j < 4; j++) pA[j] = pA0 + (size_t)j * 64 * KDIM;
    }
    const unsigned short* pB0 = Bb + (size_t)rA * KDIM + sSl;

#define STAGEALL(tt) { \
        char* base_ = ldsraw + (((tt) & 1) << 16); \
        size_t kadd_ = (size_t)(tt) * 64; \
        _Pragma("unroll") for (int j_ = 0; j_ < 4; j_++) { \
            gload_lds16(pA[j_] + kadd_, base_ + j_ * 8192 + wv * 1024); \
            gload_lds16(pB0 + (size_t)j_ * 64 * KDIM + kadd_, \
                        base_ + 32768 + j_ * 8192 + wv * 1024); \
        } }

    int physk0 = (lane >> 4) ^ (lane & 7);
    int kdel = ((physk0 ^ 4) - physk0) * 16;  // +-64
    const char* aB0k0 = ldsraw + wr * 16384 + (lane & 15) * 128 + physk0 * 16;
    const char* aB0k1 = aB0k0 + kdel;
    const char* bB0k0 = ldsraw + 32768 + (wcol >> 1) * 16384 +
                        ((wcol & 1) * 64 + (lane & 15)) * 128 + physk0 * 16;
    const char* bB0k1 = bB0k0 + kdel;

    short8 afA[4][2], afB[4][2], bfA[2][2], bfB[2][2];
    f32x4 acc[8][4];
#pragma unroll
    for (int m = 0; m < 8; m++)
#pragma unroll
        for (int n = 0; n < 4; n++) acc[m][n] = f32x4{0.f, 0.f, 0.f, 0.f};

#define LDA(DST, K0, K1, MOFF) \
    _Pragma("unroll") for (int mm = 0; mm < 4; mm++) { \
        DST[mm][0] = *(const short8*)((K0) + ((MOFF) + mm) * 2048); \
        DST[mm][1] = *(const short8*)((K1) + ((MOFF) + mm) * 2048); }
#define LDB(DST, K0, K1, NOFF) \
    _Pragma("unroll") for (int nn = 0; nn < 2; nn++) { \
        DST[nn][0] = *(const short8*)((K0) + ((NOFF) + nn) * 2048); \
        DST[nn][1] = *(const short8*)((K1) + ((NOFF) + nn) * 2048); }
#define QUAD(AF, BF, MB, NB) \
    __builtin_amdgcn_s_setprio(1); \
    _Pragma("unroll") for (int kk = 0; kk < 2; kk++) \
    _Pragma("unroll") for (int mm = 0; mm < 4; mm++) \
    _Pragma("unroll") for (int nn = 0; nn < 2; nn++) \
        acc[(MB) + mm][(NB) + nn] = __builtin_amdgcn_mfma_f32_16x16x32_bf16( \
            AF[mm][kk], BF[nn][kk], acc[(MB) + mm][(NB) + nn], 0, 0, 0); \
    __builtin_amdgcn_s_setprio(0);
#define SB() __builtin_amdgcn_sched_barrier(0)

    constexpr int T = KLEN / 64;

    STAGEALL(0)
    SB(); asm volatile("s_waitcnt vmcnt(0)" ::: "memory"); SB();
    __builtin_amdgcn_s_barrier(); SB();

#pragma unroll 1
    for (int t = 0; t < T; ++t) {
        if (t + 1 < T) STAGEALL(t + 1)
        const char* ak0 = aB0k0 + ((t & 1) << 16);
        const char* ak1 = aB0k1 + ((t & 1) << 16);
        const char* bk0 = bB0k0 + ((t & 1) << 16);
        const char* bk1 = bB0k1 + ((t & 1) << 16);
        LDA(afA, ak0, ak1, 0)
        LDB(bfA, bk0, bk1, 0)
        LDB(bfB, bk0, bk1, 2)
        QUAD(afA, bfA, 0, 0)
        LDA(afB, ak0, ak1, 4)
        QUAD(afA, bfB, 0, 2)
        QUAD(afB, bfA, 4, 0)
        QUAD(afB, bfB, 4, 2)
        SB();
        asm volatile("s_waitcnt vmcnt(0)" ::: "memory");
        SB();
        __builtin_amdgcn_s_barrier();
        SB();
    }
#undef STAGEALL
#undef LDA
#undef LDB
#undef QUAD

    // Unified epilogue: bf16 via LDS repack with rr-XOR swizzle.
    float bv[4];
    bool addBias = (MODE == 1) || (blockIdx.z == 0);
#pragma unroll
    for (int n = 0; n < 4; n++)
        bv[n] = addBias ? bias[(size_t)e * NDIM + colBase + wcol * 64 + n * 16 + (lane & 15)]
                        : 0.f;
    unsigned short* OutP = (MODE == 1) ? OutH : (blockIdx.z == 0 ? OutC0 : OutC1);

    unsigned short* lds16 = (unsigned short*)ldsraw;
#pragma unroll
    for (int m = 0; m < 8; m++) {
#pragma unroll
        for (int n = 0; n < 4; n++) {
#pragma unroll
            for (int j = 0; j < 4; j++) {
                float v = acc[m][n][j] + bv[n];
                if (MODE == 1) v = fmaxf(v, 0.f);
                int rr = wr * 128 + m * 16 + (lane >> 4) * 4 + j;
                int cc = wcol * 64 + n * 16 + (lane & 15);
                lds16[rr * 256 + (cc ^ ((rr & 7) << 4))] = f2bf(v);
            }
        }
    }
    __syncthreads();
    {
        int row = tid >> 1, half = tid & 1;
        int xr = (row & 7) << 4;
#pragma unroll
        for (int i = 0; i < 16; i++) {
            int cs = half * 128 + i * 8;
            short8 val = *(const short8*)(lds16 + row * 256 + (cs ^ xr));
            *(short8*)(OutP + (size_t)(rowBase + row) * NDIM + colBase + cs) = val;
        }
    }
}

// out[t] = w0*(c0[p0]+c1[p0]) + w1*(c0[p1]+c1[p1])  (fixed order, deterministic)
__global__ void combine_kernel(const unsigned short* __restrict__ c0,
                               const unsigned short* __restrict__ c1,
                               const int2* __restrict__ tok_pos, const float2* __restrict__ tok_w,
                               float* __restrict__ out) {
    int t = blockIdx.x;
    int2 p = tok_pos[t];
    float2 w = tok_w[t];
    int i = threadIdx.x;  // 256 x 4 elems
    ushort4 a0 = ((const ushort4*)(c0 + (size_t)p.x * C_DIM))[i];
    ushort4 a1 = ((const ushort4*)(c1 + (size_t)p.x * C_DIM))[i];
    ushort4 b0 = ((const ushort4*)(c0 + (size_t)p.y * C_DIM))[i];
    ushort4 b1 = ((const ushort4*)(c1 + (size_t)p.y * C_DIM))[i];
    float4 r;
    r.x = w.x * (bf2f(a0.x) + bf2f(a1.x)) + w.y * (bf2f(b0.x) + bf2f(b1.x));
    r.y = w.x * (bf2f(a0.y) + bf2f(a1.y)) + w.y * (bf2f(b0.y) + bf2f(b1.y));
    r.z = w.x * (bf2f(a0.z) + bf2f(a1.z)) + w.y * (bf2f(b0.z) + bf2f(b1.z));
    r.w = w.x * (bf2f(a0.w) + bf2f(a1.w)) + w.y * (bf2f(b0.w) + bf2f(b1.w));
    ((float4*)(out + (size_t)t * C_DIM))[i] = r;
}

extern "C" void kernel_launch(void* const* d_in, const int* in_sizes, int n_in,
                              void* d_out, int out_size, void* d_ws, size_t ws_size,
                              hipStream_t stream) {
    (void)in_sizes; (void)n_in; (void)out_size; (void)ws_size;
    const float* x       = (const float*)d_in[0];
    const float* noise   = (const float*)d_in[1];
    const float* w_gate  = (const float*)d_in[2];
    const float* b_gate  = (const float*)d_in[3];
    const float* w_noise = (const float*)d_in[4];
    const float* b_noise = (const float*)d_in[5];
    const float* w1      = (const float*)d_in[6];
    const float* b1      = (const float*)d_in[7];
    const float* w2      = (const float*)d_in[8];
    const float* b2      = (const float*)d_in[9];
    float* out = (float*)d_out;

    char* w = (char*)d_ws;
    size_t off = 0;
    int* meta = (int*)(w + off); off += 256;
    float* wT = (float*)(w + off); off += 16 * C_DIM * 4;
    int2* tok_e = (int2*)(w + off); off += (size_t)NTOK * 8;
    float2* tok_w = (float2*)(w + off); off += (size_t)NTOK * 8;
    int2* tok_pos = (int2*)(w + off); off += (size_t)NTOK * 8;
    int* rowtok = (int*)(w + off); off += (size_t)MAXROWS * 4;
    unsigned short* H = (unsigned short*)(w + off); off += (size_t)MAXROWS * DFF_DIM * 2;
    unsigned short* w2b = (unsigned short*)(w + off); off += (size_t)E_NUM * C_DIM * DFF_DIM * 2;
    unsigned short* c0 = (unsigned short*)(w + off); off += (size_t)MAXROWS * C_DIM * 2;
    unsigned short* c1 = (unsigned short*)(w + off); off += (size_t)MAXROWS * C_DIM * 2;
    unsigned short* xb = (unsigned short*)(w + off); off += (size_t)NTOK * C_DIM * 2;
    unsigned short* w1b = (unsigned short*)(w + off); off += (size_t)E_NUM * DFF_DIM * C_DIM * 2;

    init_kernel<<<(MAXROWS + 255) / 256, 256, 0, stream>>>(meta, rowtok, w_gate, w_noise, wT);

    hipFuncSetAttribute((const void*)router_kernel,
                        hipFuncAttributeMaxDynamicSharedMemorySize, 65536);
    router_kernel<<<NTOK / 32, 256, 65536, stream>>>(x, noise, wT, b_gate, b_noise,
                                                     meta, tok_e, tok_w);
    offsets_kernel<<<1, 64, 0, stream>>>(meta);
    assign_kernel<<<NTOK / 256, 256, 0, stream>>>(meta, tok_e, tok_pos, rowtok);
    prep_kernel<<<NB_T1 + NB_T2 + NTOK, 256, 0, stream>>>(w1, w1b, w2, w2b, x, xb);

    hipFuncSetAttribute((const void*)gemm8_kernel<C_DIM, C_DIM, DFF_DIM, 1, true>,
                        hipFuncAttributeMaxDynamicSharedMemorySize, 131072);
    gemm8_kernel<C_DIM, C_DIM, DFF_DIM, 1, true>
        <<<dim3((MAXROWS / 256) * (DFF_DIM / 256), 1, 1), 512, 131072, stream>>>(
            xb, w1b, b1, H, nullptr, nullptr, meta, rowtok);

    hipFuncSetAttribute((const void*)gemm8_kernel<DFF_DIM, DFF_DIM / 2, C_DIM, 2, false>,
                        hipFuncAttributeMaxDynamicSharedMemorySize, 131072);
    gemm8_kernel<DFF_DIM, DFF_DIM / 2, C_DIM, 2, false>
        <<<dim3((MAXROWS / 256) * (C_DIM / 256), 1, 2), 512, 131072, stream>>>(
            H, w2b, b2, nullptr, c0, c1, meta, nullptr);

    combine_kernel<<<NTOK, 256, 0, stream>>>(c0, c1, tok_pos, tok_w, out);
}

// Round 14
// 589.335 us; speedup vs baseline: 1.4887x; 1.0628x over previous
//
#include <hip/hip_runtime.h>
#include <hip/hip_bf16.h>
#include <cmath>

#define DEVFN __device__ __forceinline__

typedef __attribute__((ext_vector_type(8))) short short8;
typedef __attribute__((ext_vector_type(4))) float f32x4;

constexpr int C_DIM   = 1024;
constexpr int E_NUM   = 8;
constexpr int DFF_DIM = 4096;
constexpr int NTOK    = 8192;       // B*T
constexpr int PAD     = 256;        // expert segment alignment
constexpr int MAXROWS = NTOK * 2 + E_NUM * PAD;  // 18432

DEVFN unsigned short f2bf(float f) {
    __hip_bfloat16 h = __float2bfloat16(f);
    return __builtin_bit_cast(unsigned short, h);
}
DEVFN float bf2f(unsigned short u) {
    return __bfloat162float(__builtin_bit_cast(__hip_bfloat16, u));
}
DEVFN void gload_lds16(const void* g, void* lds) {
    __builtin_amdgcn_global_load_lds(
        (const __attribute__((address_space(1))) unsigned int*)g,
        (__attribute__((address_space(3))) unsigned int*)lds, 16, 0, 0);
}

// meta layout (ints): [0..7] counts, [8..15] cursor, [16..24] offs (offs[8]=padTotal)

// init: zero meta + rowtok, and build wT[o][c] (o<8 gate, o>=8 noise).
__global__ void init_kernel(int* meta, int* rowtok,
                            const float* __restrict__ wg, const float* __restrict__ wn,
                            float* __restrict__ wT) {
    int gid = blockIdx.x * 256 + threadIdx.x;
    if (gid < 64) meta[gid] = 0;
    if (gid < MAXROWS) rowtok[gid] = 0;
    if (gid < 16 * C_DIM) {
        int o = gid >> 10, c = gid & 1023;
        wT[gid] = (o < 8) ? wg[c * 8 + o] : wn[c * 8 + (o - 8)];
    }
}

// Transpose body: [R][S] fp32 tile (r0,s0) -> [S][R] bf16, 64x64, via lds tile
// (stride 68 floats). Writes as 2x short8 (16B stores).
DEVFN void transpose_body(const float* __restrict__ ine, unsigned short* __restrict__ oute,
                          int R, int S, int r0, int s0, float* tile) {
    int tid = threadIdx.x;
    int rr = tid >> 2, cs = (tid & 3) * 16;
    const float4* src = (const float4*)(ine + (size_t)(r0 + rr) * S + s0 + cs);
#pragma unroll
    for (int q = 0; q < 4; q++) *(float4*)&tile[rr * 68 + cs + q * 4] = src[q];
    __syncthreads();
    int ss = tid >> 2, rs = (tid & 3) * 16;
    short8 v0, v1;
#pragma unroll
    for (int q = 0; q < 8; q++) v0[q] = (short)f2bf(tile[(rs + q) * 68 + ss]);
#pragma unroll
    for (int q = 0; q < 8; q++) v1[q] = (short)f2bf(tile[(rs + 8 + q) * 68 + ss]);
    unsigned short* dst = oute + (size_t)(s0 + ss) * R + r0 + rs;
    *(short8*)dst = v0;
    *(short8*)(dst + 8) = v1;
}

// fused: {router (256 blocks), transpose w1, transpose w2, convert x->bf16}.
// Router: 32 tokens/block, 8 threads/token; wT chunked through 16KB LDS
// windows (4 chunks along C); fp64 accumulation in ascending-c order ->
// bit-identical to the R11-R13 router. Prep blocks use the same dynamic LDS
// as the 64x68 transpose tile (17408 B).
constexpr int NB_RT = 256;
constexpr int NB_T1 = (DFF_DIM / 64) * (C_DIM / 64) * E_NUM;  // 8192
constexpr int NB_T2 = (C_DIM / 64) * (DFF_DIM / 64) * E_NUM;  // 8192
__global__ __launch_bounds__(256) void fused_kernel(
    const float* __restrict__ x, const float* __restrict__ noise,
    const float* __restrict__ wT, const float* __restrict__ bg,
    const float* __restrict__ bn, int* meta, int2* tok_e, float2* tok_w,
    const float* __restrict__ w1, unsigned short* __restrict__ w1b,
    const float* __restrict__ w2, unsigned short* __restrict__ w2b,
    unsigned short* __restrict__ xb) {
    extern __shared__ float lds[];  // 17408 bytes
    int b = blockIdx.x;
    int tid = threadIdx.x;

    if (b < NB_RT) {
        // ---- router ----
        int tt = tid >> 3, sub = tid & 7;
        int tok = b * 32 + tt;
        const float* xr = x + (size_t)tok * C_DIM;
        double acc[16];
#pragma unroll
        for (int o = 0; o < 16; o++) acc[o] = 0.0;

        for (int ci = 0; ci < 4; ci++) {
            __syncthreads();
            // stage wT[0..16)[ci*256..+256) -> lds (linear o*256 + c_local)
#pragma unroll
            for (int j = 0; j < 4; j++) {
                int qd = j * 256 + tid;             // float4 index
                int o = qd >> 6, cc = (qd & 63) * 4;
                *(float4*)&lds[qd * 4] = *(const float4*)&wT[o * C_DIM + ci * 256 + cc];
            }
            __syncthreads();
#pragma unroll 4
            for (int i = 0; i < 8; i++) {
                int cl = i * 32 + sub * 4;
                float4 xv = *(const float4*)(xr + ci * 256 + cl);
#pragma unroll
                for (int o = 0; o < 16; o++) {
                    float4 wv = *(const float4*)&lds[o * 256 + cl];
                    acc[o] += (double)xv.x * (double)wv.x;
                    acc[o] += (double)xv.y * (double)wv.y;
                    acc[o] += (double)xv.z * (double)wv.z;
                    acc[o] += (double)xv.w * (double)wv.w;
                }
            }
        }
#pragma unroll
        for (int s = 1; s <= 4; s <<= 1) {
#pragma unroll
            for (int o = 0; o < 16; o++) acc[o] += __shfl_xor(acc[o], s, 64);
        }
        if (sub == 0) {
            double logit[8];
#pragma unroll
            for (int e = 0; e < 8; e++) {
                double cl = acc[e] + (double)bg[e];
                double nl = acc[8 + e] + (double)bn[e];
                double sp = (nl > 30.0) ? nl : log1p(exp(nl));
                logit[e] = cl + (double)noise[(size_t)tok * 8 + e] * sp;
            }
            int i1 = -1, i2 = -1;
            double v1 = -1e300, v2 = -1e300;
#pragma unroll
            for (int e = 0; e < 8; e++) {
                double v = logit[e];
                if (v > v1) { v2 = v1; i2 = i1; v1 = v; i1 = e; }
                else if (v > v2) { v2 = v; i2 = e; }
            }
            double d = exp(v2 - v1);
            tok_e[tok] = make_int2(i1, i2);
            tok_w[tok] = make_float2((float)(1.0 / (1.0 + d)), (float)(d / (1.0 + d)));
            atomicAdd(&meta[i1], 1);
            atomicAdd(&meta[i2], 1);
        }
        return;
    }
    b -= NB_RT;
    if (b < NB_T1) {
        int bx = b & 63, by = (b >> 6) & 15, bz = b >> 10;
        transpose_body(w1 + (size_t)bz * C_DIM * DFF_DIM,
                       w1b + (size_t)bz * C_DIM * DFF_DIM,
                       C_DIM, DFF_DIM, by * 64, bx * 64, lds);
        return;
    }
    b -= NB_T1;
    if (b < NB_T2) {
        int bx = b & 15, by = (b >> 4) & 63, bz = b >> 10;
        transpose_body(w2 + (size_t)bz * C_DIM * DFF_DIM,
                       w2b + (size_t)bz * C_DIM * DFF_DIM,
                       DFF_DIM, C_DIM, by * 64, bx * 64, lds);
        return;
    }
    b -= NB_T2;
    // convert token row b: x fp32 -> xb bf16 (token order)
    const float4* src = (const float4*)(x + (size_t)b * C_DIM);
    ushort4* dst = (ushort4*)(xb + (size_t)b * C_DIM);
    int i = tid;
    float4 v = src[i];
    ushort4 o;
    o.x = f2bf(v.x); o.y = f2bf(v.y); o.z = f2bf(v.z); o.w = f2bf(v.w);
    dst[i] = o;
}

__global__ void offsets_kernel(int* meta) {
    if (threadIdx.x == 0 && blockIdx.x == 0) {
        int off = 0;
        for (int e = 0; e < 8; e++) {
            meta[16 + e] = off;
            off += (meta[e] + PAD - 1) / PAD * PAD;
            meta[8 + e] = 0;  // cursor
        }
        meta[24] = off;  // padTotal
    }
}

// Wave-aggregated slot assignment (atomic order doesn't affect any FP result).
__global__ void assign_kernel(int* meta, const int2* tok_e,
                              int2* tok_pos, int* rowtok) {
    int t = blockIdx.x * 256 + threadIdx.x;
    int lane = threadIdx.x & 63;
    int2 e = tok_e[t];
    int sel[2] = {e.x, e.y};
    int pos[2];
#pragma unroll
    for (int s = 0; s < 2; s++) {
        int p = 0;
#pragma unroll
        for (int ex = 0; ex < 8; ex++) {
            unsigned long long m = __ballot(sel[s] == ex);
            if (m) {
                int leader = __ffsll((unsigned long long)m) - 1;
                int base = 0;
                if (lane == leader) base = atomicAdd(&meta[8 + ex], (int)__popcll(m));
                base = __shfl(base, leader, 64);
                if (sel[s] == ex)
                    p = meta[16 + ex] + base + (int)__popcll(m & ((1ull << lane) - 1ull));
            }
        }
        pos[s] = p;
        rowtok[p] = t;
    }
    tok_pos[t] = make_int2(pos[0], pos[1]);
}

// ---------------------------------------------------------------------------
// 256x256 GEMM (measured-best R8/R11 structure), 512 thr = 8 waves (2M x 4N),
// BK=64, dbuf x2 (2 x 64KB LDS). Per K-tile: stage(t+1) (8 gload_lds), then
// 24 ds_read + 64 MFMA free-scheduled, ONE vmcnt(0) + ONE s_barrier.
// Swizzle: 128B rows, 16B slot s at phys s^(row&7) on gload SOURCE + read.
// INDIR: A-rows fetched via rowtok indirection from token-ordered xb.
// MODE 1: relu(acc+bias) -> OutH.  MODE 2: acc + (z==0)*bias -> OutC{z}.
// ---------------------------------------------------------------------------
template <int KDIM, int KLEN, int NDIM, int MODE, bool INDIR>
__global__ __launch_bounds__(512, 2) void gemm8_kernel(
    const unsigned short* __restrict__ A, const unsigned short* __restrict__ Bt,
    const float* __restrict__ bias, unsigned short* __restrict__ OutH,
    unsigned short* __restrict__ OutC0, unsigned short* __restrict__ OutC1,
    const int* __restrict__ meta, const int* __restrict__ rowtok) {
    extern __shared__ char ldsraw[];  // 131072 bytes

    int nwg = gridDim.x;
    int orig = blockIdx.x;
    int q = nwg >> 3, r8 = nwg & 7;
    int xcd = orig & 7, idx = orig >> 3;
    int wgid = (xcd < r8 ? xcd * (q + 1) : r8 * (q + 1) + (xcd - r8) * q) + idx;
    constexpr int NCT = NDIM / 256;
    int rowBase = (wgid / NCT) * 256;
    int colBase = (wgid % NCT) * 256;
    if (rowBase >= meta[24]) return;
    int e = 0;
#pragma unroll
    for (int i = 1; i < 8; i++)
        if (rowBase >= meta[16 + i]) e = i;
    int koff = blockIdx.z * KLEN;

    int tid = threadIdx.x;
    int wv = tid >> 6, lane = tid & 63;
    int wr = wv >> 2, wcol = wv & 3;  // 2M x 4N waves; wave output 128x64

    const unsigned short* Bb = Bt + (size_t)e * NDIM * KDIM + (size_t)colBase * KDIM + koff;

    int rA = tid >> 3;
    int sSl = ((tid & 7) ^ (rA & 7)) * 8;
    const unsigned short* pA[4];
    if constexpr (INDIR) {
#pragma unroll
        for (int j = 0; j < 4; j++) {
            int tok = rowtok[rowBase + rA + j * 64];
            pA[j] = A + (size_t)tok * KDIM + sSl + koff;
        }
    } else {
        const unsigned short* pA0 = A + (size_t)(rowBase + rA) * KDIM + sSl + koff;
#pragma unroll
        for (int j = 0; j < 4; j++) pA[j] = pA0 + (size_t)j * 64 * KDIM;
    }
    const unsigned short* pB0 = Bb + (size_t)rA * KDIM + sSl;

#define STAGEALL(tt) { \
        char* base_ = ldsraw + (((tt) & 1) << 16); \
        size_t kadd_ = (size_t)(tt) * 64; \
        _Pragma("unroll") for (int j_ = 0; j_ < 4; j_++) { \
            gload_lds16(pA[j_] + kadd_, base_ + j_ * 8192 + wv * 1024); \
            gload_lds16(pB0 + (size_t)j_ * 64 * KDIM + kadd_, \
                        base_ + 32768 + j_ * 8192 + wv * 1024); \
        } }

    int physk0 = (lane >> 4) ^ (lane & 7);
    int kdel = ((physk0 ^ 4) - physk0) * 16;  // +-64
    const char* aB0k0 = ldsraw + wr * 16384 + (lane & 15) * 128 + physk0 * 16;
    const char* aB0k1 = aB0k0 + kdel;
    const char* bB0k0 = ldsraw + 32768 + (wcol >> 1) * 16384 +
                        ((wcol & 1) * 64 + (lane & 15)) * 128 + physk0 * 16;
    const char* bB0k1 = bB0k0 + kdel;

    short8 afA[4][2], afB[4][2], bfA[2][2], bfB[2][2];
    f32x4 acc[8][4];
#pragma unroll
    for (int m = 0; m < 8; m++)
#pragma unroll
        for (int n = 0; n < 4; n++) acc[m][n] = f32x4{0.f, 0.f, 0.f, 0.f};

#define LDA(DST, K0, K1, MOFF) \
    _Pragma("unroll") for (int mm = 0; mm < 4; mm++) { \
        DST[mm][0] = *(const short8*)((K0) + ((MOFF) + mm) * 2048); \
        DST[mm][1] = *(const short8*)((K1) + ((MOFF) + mm) * 2048); }
#define LDB(DST, K0, K1, NOFF) \
    _Pragma("unroll") for (int nn = 0; nn < 2; nn++) { \
        DST[nn][0] = *(const short8*)((K0) + ((NOFF) + nn) * 2048); \
        DST[nn][1] = *(const short8*)((K1) + ((NOFF) + nn) * 2048); }
#define QUAD(AF, BF, MB, NB) \
    __builtin_amdgcn_s_setprio(1); \
    _Pragma("unroll") for (int kk = 0; kk < 2; kk++) \
    _Pragma("unroll") for (int mm = 0; mm < 4; mm++) \
    _Pragma("unroll") for (int nn = 0; nn < 2; nn++) \
        acc[(MB) + mm][(NB) + nn] = __builtin_amdgcn_mfma_f32_16x16x32_bf16( \
            AF[mm][kk], BF[nn][kk], acc[(MB) + mm][(NB) + nn], 0, 0, 0); \
    __builtin_amdgcn_s_setprio(0);
#define SB() __builtin_amdgcn_sched_barrier(0)

    constexpr int T = KLEN / 64;

    STAGEALL(0)
    SB(); asm volatile("s_waitcnt vmcnt(0)" ::: "memory"); SB();
    __builtin_amdgcn_s_barrier(); SB();

#pragma unroll 1
    for (int t = 0; t < T; ++t) {
        if (t + 1 < T) STAGEALL(t + 1)
        const char* ak0 = aB0k0 + ((t & 1) << 16);
        const char* ak1 = aB0k1 + ((t & 1) << 16);
        const char* bk0 = bB0k0 + ((t & 1) << 16);
        const char* bk1 = bB0k1 + ((t & 1) << 16);
        LDA(afA, ak0, ak1, 0)
        LDB(bfA, bk0, bk1, 0)
        LDB(bfB, bk0, bk1, 2)
        QUAD(afA, bfA, 0, 0)
        LDA(afB, ak0, ak1, 4)
        QUAD(afA, bfB, 0, 2)
        QUAD(afB, bfA, 4, 0)
        QUAD(afB, bfB, 4, 2)
        SB();
        asm volatile("s_waitcnt vmcnt(0)" ::: "memory");
        SB();
        __builtin_amdgcn_s_barrier();
        SB();
    }
#undef STAGEALL
#undef LDA
#undef LDB
#undef QUAD

    // Unified epilogue: bf16 via LDS repack with rr-XOR swizzle.
    float bv[4];
    bool addBias = (MODE == 1) || (blockIdx.z == 0);
#pragma unroll
    for (int n = 0; n < 4; n++)
        bv[n] = addBias ? bias[(size_t)e * NDIM + colBase + wcol * 64 + n * 16 + (lane & 15)]
                        : 0.f;
    unsigned short* OutP = (MODE == 1) ? OutH : (blockIdx.z == 0 ? OutC0 : OutC1);

    unsigned short* lds16 = (unsigned short*)ldsraw;
#pragma unroll
    for (int m = 0; m < 8; m++) {
#pragma unroll
        for (int n = 0; n < 4; n++) {
#pragma unroll
            for (int j = 0; j < 4; j++) {
                float v = acc[m][n][j] + bv[n];
                if (MODE == 1) v = fmaxf(v, 0.f);
                int rr = wr * 128 + m * 16 + (lane >> 4) * 4 + j;
                int cc = wcol * 64 + n * 16 + (lane & 15);
                lds16[rr * 256 + (cc ^ ((rr & 7) << 4))] = f2bf(v);
            }
        }
    }
    __syncthreads();
    {
        int row = tid >> 1, half = tid & 1;
        int xr = (row & 7) << 4;
#pragma unroll
        for (int i = 0; i < 16; i++) {
            int cs = half * 128 + i * 8;
            short8 val = *(const short8*)(lds16 + row * 256 + (cs ^ xr));
            *(short8*)(OutP + (size_t)(rowBase + row) * NDIM + colBase + cs) = val;
        }
    }
}

// out[t] = w0*(c0[p0]+c1[p0]) + w1*(c0[p1]+c1[p1])  (fixed order, deterministic)
__global__ void combine_kernel(const unsigned short* __restrict__ c0,
                               const unsigned short* __restrict__ c1,
                               const int2* __restrict__ tok_pos, const float2* __restrict__ tok_w,
                               float* __restrict__ out) {
    int t = blockIdx.x;
    int2 p = tok_pos[t];
    float2 w = tok_w[t];
    int i = threadIdx.x;  // 256 x 4 elems
    ushort4 a0 = ((const ushort4*)(c0 + (size_t)p.x * C_DIM))[i];
    ushort4 a1 = ((const ushort4*)(c1 + (size_t)p.x * C_DIM))[i];
    ushort4 b0 = ((const ushort4*)(c0 + (size_t)p.y * C_DIM))[i];
    ushort4 b1 = ((const ushort4*)(c1 + (size_t)p.y * C_DIM))[i];
    float4 r;
    r.x = w.x * (bf2f(a0.x) + bf2f(a1.x)) + w.y * (bf2f(b0.x) + bf2f(b1.x));
    r.y = w.x * (bf2f(a0.y) + bf2f(a1.y)) + w.y * (bf2f(b0.y) + bf2f(b1.y));
    r.z = w.x * (bf2f(a0.z) + bf2f(a1.z)) + w.y * (bf2f(b0.z) + bf2f(b1.z));
    r.w = w.x * (bf2f(a0.w) + bf2f(a1.w)) + w.y * (bf2f(b0.w) + bf2f(b1.w));
    ((float4*)(out + (size_t)t * C_DIM))[i] = r;
}

extern "C" void kernel_launch(void* const* d_in, const int* in_sizes, int n_in,
                              void* d_out, int out_size, void* d_ws, size_t ws_size,
                              hipStream_t stream) {
    (void)in_sizes; (void)n_in; (void)out_size; (void)ws_size;
    const float* x       = (const float*)d_in[0];
    const float* noise   = (const float*)d_in[1];
    const float* w_gate  = (const float*)d_in[2];
    const float* b_gate  = (const float*)d_in[3];
    const float* w_noise = (const float*)d_in[4];
    const float* b_noise = (const float*)d_in[5];
    const float* w1      = (const float*)d_in[6];
    const float* b1      = (const float*)d_in[7];
    const float* w2      = (const float*)d_in[8];
    const float* b2      = (const float*)d_in[9];
    float* out = (float*)d_out;

    char* w = (char*)d_ws;
    size_t off = 0;
    int* meta = (int*)(w + off); off += 256;
    float* wT = (float*)(w + off); off += 16 * C_DIM * 4;
    int2* tok_e = (int2*)(w + off); off += (size_t)NTOK * 8;
    float2* tok_w = (float2*)(w + off); off += (size_t)NTOK * 8;
    int2* tok_pos = (int2*)(w + off); off += (size_t)NTOK * 8;
    int* rowtok = (int*)(w + off); off += (size_t)MAXROWS * 4;
    unsigned short* H = (unsigned short*)(w + off); off += (size_t)MAXROWS * DFF_DIM * 2;
    unsigned short* w2b = (unsigned short*)(w + off); off += (size_t)E_NUM * C_DIM * DFF_DIM * 2;
    unsigned short* c0 = (unsigned short*)(w + off); off += (size_t)MAXROWS * C_DIM * 2;
    unsigned short* c1 = (unsigned short*)(w + off); off += (size_t)MAXROWS * C_DIM * 2;
    unsigned short* xb = (unsigned short*)(w + off); off += (size_t)NTOK * C_DIM * 2;
    unsigned short* w1b = (unsigned short*)(w + off); off += (size_t)E_NUM * DFF_DIM * C_DIM * 2;

    init_kernel<<<(MAXROWS + 255) / 256, 256, 0, stream>>>(meta, rowtok, w_gate, w_noise, wT);

    fused_kernel<<<NB_RT + NB_T1 + NB_T2 + NTOK, 256, 17408, stream>>>(
        x, noise, wT, b_gate, b_noise, meta, tok_e, tok_w,
        w1, w1b, w2, w2b, xb);

    offsets_kernel<<<1, 64, 0, stream>>>(meta);
    assign_kernel<<<NTOK / 256, 256, 0, stream>>>(meta, tok_e, tok_pos, rowtok);

    hipFuncSetAttribute((const void*)gemm8_kernel<C_DIM, C_DIM, DFF_DIM, 1, true>,
                        hipFuncAttributeMaxDynamicSharedMemorySize, 131072);
    gemm8_kernel<C_DIM, C_DIM, DFF_DIM, 1, true>
        <<<dim3((MAXROWS / 256) * (DFF_DIM / 256), 1, 1), 512, 131072, stream>>>(
            xb, w1b, b1, H, nullptr, nullptr, meta, rowtok);

    hipFuncSetAttribute((const void*)gemm8_kernel<DFF_DIM, DFF_DIM / 2, C_DIM, 2, false>,
                        hipFuncAttributeMaxDynamicSharedMemorySize, 131072);
    gemm8_kernel<DFF_DIM, DFF_DIM / 2, C_DIM, 2, false>
        <<<dim3((MAXROWS / 256) * (C_DIM / 256), 1, 2), 512, 131072, stream>>>(
            H, w2b, b2, nullptr, c0, c1, meta, nullptr);

    combine_kernel<<<NTOK, 256, 0, stream>>>(c0, c1, tok_pos, tok_w, out);
}

// Round 15
// 584.832 us; speedup vs baseline: 1.5002x; 1.0077x over previous
//
#include <hip/hip_runtime.h>
#include <hip/hip_bf16.h>
#include <cmath>

#define DEVFN __device__ __forceinline__

typedef __attribute__((ext_vector_type(8))) short short8;
typedef __attribute__((ext_vector_type(4))) float f32x4;

constexpr int C_DIM   = 1024;
constexpr int E_NUM   = 8;
constexpr int DFF_DIM = 4096;
constexpr int NTOK    = 8192;       // B*T
constexpr int PAD     = 256;        // expert segment alignment
constexpr int MAXROWS = NTOK * 2 + E_NUM * PAD;  // 18432

DEVFN unsigned short f2bf(float f) {
    __hip_bfloat16 h = __float2bfloat16(f);
    return __builtin_bit_cast(unsigned short, h);
}
DEVFN float bf2f(unsigned short u) {
    return __bfloat162float(__builtin_bit_cast(__hip_bfloat16, u));
}
DEVFN void gload_lds16(const void* g, void* lds) {
    __builtin_amdgcn_global_load_lds(
        (const __attribute__((address_space(1))) unsigned int*)g,
        (__attribute__((address_space(3))) unsigned int*)lds, 16, 0, 0);
}

// meta layout (ints): [0..7] counts, [8..15] cursor, [16..24] offs (offs[8]=padTotal)
// meta[0..63] zeroed via hipMemsetAsync before fused_kernel.

// Transpose body: [R][S] fp32 tile (r0,s0) -> [S][R] bf16, 64x64, via lds tile
// (stride 68 floats). Writes as 2x short8 (16B stores).
DEVFN void transpose_body(const float* __restrict__ ine, unsigned short* __restrict__ oute,
                          int R, int S, int r0, int s0, float* tile) {
    int tid = threadIdx.x;
    int rr = tid >> 2, cs = (tid & 3) * 16;
    const float4* src = (const float4*)(ine + (size_t)(r0 + rr) * S + s0 + cs);
#pragma unroll
    for (int q = 0; q < 4; q++) *(float4*)&tile[rr * 68 + cs + q * 4] = src[q];
    __syncthreads();
    int ss = tid >> 2, rs = (tid & 3) * 16;
    short8 v0, v1;
#pragma unroll
    for (int q = 0; q < 8; q++) v0[q] = (short)f2bf(tile[(rs + q) * 68 + ss]);
#pragma unroll
    for (int q = 0; q < 8; q++) v1[q] = (short)f2bf(tile[(rs + 8 + q) * 68 + ss]);
    unsigned short* dst = oute + (size_t)(s0 + ss) * R + r0 + rs;
    *(short8*)dst = v0;
    *(short8*)(dst + 8) = v1;
}

// fused: {router (256 blocks), transpose w1, transpose w2, convert x->bf16
// (+ rowtok zeroing in first 72 convert blocks)}.
// Router: 32 tokens/block, 8 threads/token; weights staged per 16KB LDS
// window (4 chunks along C) gathered directly from wg/wn (values identical
// to the old wT build -> bit-identical logits); fp64 accumulation in
// ascending-c order == R11-R14 router.
constexpr int NB_RT = 256;
constexpr int NB_T1 = (DFF_DIM / 64) * (C_DIM / 64) * E_NUM;  // 8192
constexpr int NB_T2 = (C_DIM / 64) * (DFF_DIM / 64) * E_NUM;  // 8192
__global__ __launch_bounds__(256) void fused_kernel(
    const float* __restrict__ x, const float* __restrict__ noise,
    const float* __restrict__ wg, const float* __restrict__ wn,
    const float* __restrict__ bg, const float* __restrict__ bn,
    int* meta, int2* tok_e, float2* tok_w, int* rowtok,
    const float* __restrict__ w1, unsigned short* __restrict__ w1b,
    const float* __restrict__ w2, unsigned short* __restrict__ w2b,
    unsigned short* __restrict__ xb) {
    extern __shared__ float lds[];  // 17408 bytes
    int b = blockIdx.x;
    int tid = threadIdx.x;

    if (b < NB_RT) {
        // ---- router ----
        int tt = tid >> 3, sub = tid & 7;
        int tok = b * 32 + tt;
        const float* xr = x + (size_t)tok * C_DIM;
        double acc[16];
#pragma unroll
        for (int o = 0; o < 16; o++) acc[o] = 0.0;

        for (int ci = 0; ci < 4; ci++) {
            __syncthreads();
            // stage weights window [o in 0..16)[c in ci*256..+256) -> lds
            // (linear o*256 + c_local), gathered from wg/wn directly.
#pragma unroll
            for (int j = 0; j < 4; j++) {
                int qd = j * 256 + tid;             // float4 index
                int o = qd >> 6, cc = (qd & 63) * 4;
                int cg = ci * 256 + cc;
                float4 v;
                if (o < 8) {
                    v.x = wg[(size_t)(cg + 0) * 8 + o];
                    v.y = wg[(size_t)(cg + 1) * 8 + o];
                    v.z = wg[(size_t)(cg + 2) * 8 + o];
                    v.w = wg[(size_t)(cg + 3) * 8 + o];
                } else {
                    int on = o - 8;
                    v.x = wn[(size_t)(cg + 0) * 8 + on];
                    v.y = wn[(size_t)(cg + 1) * 8 + on];
                    v.z = wn[(size_t)(cg + 2) * 8 + on];
                    v.w = wn[(size_t)(cg + 3) * 8 + on];
                }
                *(float4*)&lds[qd * 4] = v;
            }
            __syncthreads();
#pragma unroll 4
            for (int i = 0; i < 8; i++) {
                int cl = i * 32 + sub * 4;
                float4 xv = *(const float4*)(xr + ci * 256 + cl);
#pragma unroll
                for (int o = 0; o < 16; o++) {
                    float4 wv = *(const float4*)&lds[o * 256 + cl];
                    acc[o] += (double)xv.x * (double)wv.x;
                    acc[o] += (double)xv.y * (double)wv.y;
                    acc[o] += (double)xv.z * (double)wv.z;
                    acc[o] += (double)xv.w * (double)wv.w;
                }
            }
        }
#pragma unroll
        for (int s = 1; s <= 4; s <<= 1) {
#pragma unroll
            for (int o = 0; o < 16; o++) acc[o] += __shfl_xor(acc[o], s, 64);
        }
        if (sub == 0) {
            double logit[8];
#pragma unroll
            for (int e = 0; e < 8; e++) {
                double cl = acc[e] + (double)bg[e];
                double nl = acc[8 + e] + (double)bn[e];
                double sp = (nl > 30.0) ? nl : log1p(exp(nl));
                logit[e] = cl + (double)noise[(size_t)tok * 8 + e] * sp;
            }
            int i1 = -1, i2 = -1;
            double v1 = -1e300, v2 = -1e300;
#pragma unroll
            for (int e = 0; e < 8; e++) {
                double v = logit[e];
                if (v > v1) { v2 = v1; i2 = i1; v1 = v; i1 = e; }
                else if (v > v2) { v2 = v; i2 = e; }
            }
            double d = exp(v2 - v1);
            tok_e[tok] = make_int2(i1, i2);
            tok_w[tok] = make_float2((float)(1.0 / (1.0 + d)), (float)(d / (1.0 + d)));
            atomicAdd(&meta[i1], 1);
            atomicAdd(&meta[i2], 1);
        }
        return;
    }
    b -= NB_RT;
    if (b < NB_T1) {
        int bx = b & 63, by = (b >> 6) & 15, bz = b >> 10;
        transpose_body(w1 + (size_t)bz * C_DIM * DFF_DIM,
                       w1b + (size_t)bz * C_DIM * DFF_DIM,
                       C_DIM, DFF_DIM, by * 64, bx * 64, lds);
        return;
    }
    b -= NB_T1;
    if (b < NB_T2) {
        int bx = b & 15, by = (b >> 4) & 63, bz = b >> 10;
        transpose_body(w2 + (size_t)bz * C_DIM * DFF_DIM,
                       w2b + (size_t)bz * C_DIM * DFF_DIM,
                       DFF_DIM, C_DIM, by * 64, bx * 64, lds);
        return;
    }
    b -= NB_T2;
    // rowtok zeroing (pad rows must point at a valid token): 72*256 = MAXROWS
    if (b < 72) rowtok[b * 256 + tid] = 0;
    // convert token row b: x fp32 -> xb bf16 (token order)
    const float4* src = (const float4*)(x + (size_t)b * C_DIM);
    ushort4* dst = (ushort4*)(xb + (size_t)b * C_DIM);
    int i = tid;
    float4 v = src[i];
    ushort4 o;
    o.x = f2bf(v.x); o.y = f2bf(v.y); o.z = f2bf(v.z); o.w = f2bf(v.w);
    dst[i] = o;
}

// Wave-aggregated slot assignment with inline offsets (atomic order doesn't
// affect any FP result). Each block computes the padded prefix from
// meta[0..7]; block 0 publishes meta[16..24] for the GEMMs.
__global__ void assign_kernel(int* meta, const int2* tok_e,
                              int2* tok_pos, int* rowtok) {
    int cnt[8], offs[8];
#pragma unroll
    for (int e = 0; e < 8; e++) cnt[e] = meta[e];
    int run = 0;
#pragma unroll
    for (int e = 0; e < 8; e++) {
        offs[e] = run;
        run += (cnt[e] + PAD - 1) / PAD * PAD;
    }
    if (blockIdx.x == 0 && threadIdx.x == 0) {
#pragma unroll
        for (int e = 0; e < 8; e++) meta[16 + e] = offs[e];
        meta[24] = run;
    }

    int t = blockIdx.x * 256 + threadIdx.x;
    int lane = threadIdx.x & 63;
    int2 e = tok_e[t];
    int sel[2] = {e.x, e.y};
    int pos[2];
#pragma unroll
    for (int s = 0; s < 2; s++) {
        int p = 0;
#pragma unroll
        for (int ex = 0; ex < 8; ex++) {
            unsigned long long m = __ballot(sel[s] == ex);
            if (m) {
                int leader = __ffsll((unsigned long long)m) - 1;
                int base = 0;
                if (lane == leader) base = atomicAdd(&meta[8 + ex], (int)__popcll(m));
                base = __shfl(base, leader, 64);
                if (sel[s] == ex)
                    p = offs[ex] + base + (int)__popcll(m & ((1ull << lane) - 1ull));
            }
        }
        pos[s] = p;
        rowtok[p] = t;
    }
    tok_pos[t] = make_int2(pos[0], pos[1]);
}

// ---------------------------------------------------------------------------
// 256x256 GEMM (measured-best R8/R11 structure), 512 thr = 8 waves (2M x 4N),
// BK=64, dbuf x2 (2 x 64KB LDS). Per K-tile: stage(t+1) (8 gload_lds), then
// 24 ds_read + 64 MFMA free-scheduled, ONE vmcnt(0) + ONE s_barrier.
// Swizzle: 128B rows, 16B slot s at phys s^(row&7) on gload SOURCE + read.
// INDIR: A-rows fetched via rowtok indirection from token-ordered xb.
// MODE 1: relu(acc+bias) -> OutH.  MODE 2: acc + (z==0)*bias -> OutC{z}.
// ---------------------------------------------------------------------------
template <int KDIM, int KLEN, int NDIM, int MODE, bool INDIR>
__global__ __launch_bounds__(512, 2) void gemm8_kernel(
    const unsigned short* __restrict__ A, const unsigned short* __restrict__ Bt,
    const float* __restrict__ bias, unsigned short* __restrict__ OutH,
    unsigned short* __restrict__ OutC0, unsigned short* __restrict__ OutC1,
    const int* __restrict__ meta, const int* __restrict__ rowtok) {
    extern __shared__ char ldsraw[];  // 131072 bytes

    int nwg = gridDim.x;
    int orig = blockIdx.x;
    int q = nwg >> 3, r8 = nwg & 7;
    int xcd = orig & 7, idx = orig >> 3;
    int wgid = (xcd < r8 ? xcd * (q + 1) : r8 * (q + 1) + (xcd - r8) * q) + idx;
    constexpr int NCT = NDIM / 256;
    int rowBase = (wgid / NCT) * 256;
    int colBase = (wgid % NCT) * 256;
    if (rowBase >= meta[24]) return;
    int e = 0;
#pragma unroll
    for (int i = 1; i < 8; i++)
        if (rowBase >= meta[16 + i]) e = i;
    int koff = blockIdx.z * KLEN;

    int tid = threadIdx.x;
    int wv = tid >> 6, lane = tid & 63;
    int wr = wv >> 2, wcol = wv & 3;  // 2M x 4N waves; wave output 128x64

    const unsigned short* Bb = Bt + (size_t)e * NDIM * KDIM + (size_t)colBase * KDIM + koff;

    int rA = tid >> 3;
    int sSl = ((tid & 7) ^ (rA & 7)) * 8;
    const unsigned short* pA[4];
    if constexpr (INDIR) {
#pragma unroll
        for (int j = 0; j < 4; j++) {
            int tok = rowtok[rowBase + rA + j * 64];
            pA[j] = A + (size_t)tok * KDIM + sSl + koff;
        }
    } else {
        const unsigned short* pA0 = A + (size_t)(rowBase + rA) * KDIM + sSl + koff;
#pragma unroll
        for (int j = 0; j < 4; j++) pA[j] = pA0 + (size_t)j * 64 * KDIM;
    }
    const unsigned short* pB0 = Bb + (size_t)rA * KDIM + sSl;

#define STAGEALL(tt) { \
        char* base_ = ldsraw + (((tt) & 1) << 16); \
        size_t kadd_ = (size_t)(tt) * 64; \
        _Pragma("unroll") for (int j_ = 0; j_ < 4; j_++) { \
            gload_lds16(pA[j_] + kadd_, base_ + j_ * 8192 + wv * 1024); \
            gload_lds16(pB0 + (size_t)j_ * 64 * KDIM + kadd_, \
                        base_ + 32768 + j_ * 8192 + wv * 1024); \
        } }

    int physk0 = (lane >> 4) ^ (lane & 7);
    int kdel = ((physk0 ^ 4) - physk0) * 16;  // +-64
    const char* aB0k0 = ldsraw + wr * 16384 + (lane & 15) * 128 + physk0 * 16;
    const char* aB0k1 = aB0k0 + kdel;
    const char* bB0k0 = ldsraw + 32768 + (wcol >> 1) * 16384 +
                        ((wcol & 1) * 64 + (lane & 15)) * 128 + physk0 * 16;
    const char* bB0k1 = bB0k0 + kdel;

    short8 afA[4][2], afB[4][2], bfA[2][2], bfB[2][2];
    f32x4 acc[8][4];
#pragma unroll
    for (int m = 0; m < 8; m++)
#pragma unroll
        for (int n = 0; n < 4; n++) acc[m][n] = f32x4{0.f, 0.f, 0.f, 0.f};

#define LDA(DST, K0, K1, MOFF) \
    _Pragma("unroll") for (int mm = 0; mm < 4; mm++) { \
        DST[mm][0] = *(const short8*)((K0) + ((MOFF) + mm) * 2048); \
        DST[mm][1] = *(const short8*)((K1) + ((MOFF) + mm) * 2048); }
#define LDB(DST, K0, K1, NOFF) \
    _Pragma("unroll") for (int nn = 0; nn < 2; nn++) { \
        DST[nn][0] = *(const short8*)((K0) + ((NOFF) + nn) * 2048); \
        DST[nn][1] = *(const short8*)((K1) + ((NOFF) + nn) * 2048); }
#define QUAD(AF, BF, MB, NB) \
    __builtin_amdgcn_s_setprio(1); \
    _Pragma("unroll") for (int kk = 0; kk < 2; kk++) \
    _Pragma("unroll") for (int mm = 0; mm < 4; mm++) \
    _Pragma("unroll") for (int nn = 0; nn < 2; nn++) \
        acc[(MB) + mm][(NB) + nn] = __builtin_amdgcn_mfma_f32_16x16x32_bf16( \
            AF[mm][kk], BF[nn][kk], acc[(MB) + mm][(NB) + nn], 0, 0, 0); \
    __builtin_amdgcn_s_setprio(0);
#define SB() __builtin_amdgcn_sched_barrier(0)

    constexpr int T = KLEN / 64;

    STAGEALL(0)
    SB(); asm volatile("s_waitcnt vmcnt(0)" ::: "memory"); SB();
    __builtin_amdgcn_s_barrier(); SB();

#pragma unroll 1
    for (int t = 0; t < T; ++t) {
        if (t + 1 < T) STAGEALL(t + 1)
        const char* ak0 = aB0k0 + ((t & 1) << 16);
        const char* ak1 = aB0k1 + ((t & 1) << 16);
        const char* bk0 = bB0k0 + ((t & 1) << 16);
        const char* bk1 = bB0k1 + ((t & 1) << 16);
        LDA(afA, ak0, ak1, 0)
        LDB(bfA, bk0, bk1, 0)
        LDB(bfB, bk0, bk1, 2)
        QUAD(afA, bfA, 0, 0)
        LDA(afB, ak0, ak1, 4)
        QUAD(afA, bfB, 0, 2)
        QUAD(afB, bfA, 4, 0)
        QUAD(afB, bfB, 4, 2)
        SB();
        asm volatile("s_waitcnt vmcnt(0)" ::: "memory");
        SB();
        __builtin_amdgcn_s_barrier();
        SB();
    }
#undef STAGEALL
#undef LDA
#undef LDB
#undef QUAD

    // Unified epilogue: bf16 via LDS repack with rr-XOR swizzle.
    float bv[4];
    bool addBias = (MODE == 1) || (blockIdx.z == 0);
#pragma unroll
    for (int n = 0; n < 4; n++)
        bv[n] = addBias ? bias[(size_t)e * NDIM + colBase + wcol * 64 + n * 16 + (lane & 15)]
                        : 0.f;
    unsigned short* OutP = (MODE == 1) ? OutH : (blockIdx.z == 0 ? OutC0 : OutC1);

    unsigned short* lds16 = (unsigned short*)ldsraw;
#pragma unroll
    for (int m = 0; m < 8; m++) {
#pragma unroll
        for (int n = 0; n < 4; n++) {
#pragma unroll
            for (int j = 0; j < 4; j++) {
                float v = acc[m][n][j] + bv[n];
                if (MODE == 1) v = fmaxf(v, 0.f);
                int rr = wr * 128 + m * 16 + (lane >> 4) * 4 + j;
                int cc = wcol * 64 + n * 16 + (lane & 15);
                lds16[rr * 256 + (cc ^ ((rr & 7) << 4))] = f2bf(v);
            }
        }
    }
    __syncthreads();
    {
        int row = tid >> 1, half = tid & 1;
        int xr = (row & 7) << 4;
#pragma unroll
        for (int i = 0; i < 16; i++) {
            int cs = half * 128 + i * 8;
            short8 val = *(const short8*)(lds16 + row * 256 + (cs ^ xr));
            *(short8*)(OutP + (size_t)(rowBase + row) * NDIM + colBase + cs) = val;
        }
    }
}

// out[t] = w0*(c0[p0]+c1[p0]) + w1*(c0[p1]+c1[p1])  (fixed order, deterministic)
__global__ void combine_kernel(const unsigned short* __restrict__ c0,
                               const unsigned short* __restrict__ c1,
                               const int2* __restrict__ tok_pos, const float2* __restrict__ tok_w,
                               float* __restrict__ out) {
    int t = blockIdx.x;
    int2 p = tok_pos[t];
    float2 w = tok_w[t];
    int i = threadIdx.x;  // 256 x 4 elems
    ushort4 a0 = ((const ushort4*)(c0 + (size_t)p.x * C_DIM))[i];
    ushort4 a1 = ((const ushort4*)(c1 + (size_t)p.x * C_DIM))[i];
    ushort4 b0 = ((const ushort4*)(c0 + (size_t)p.y * C_DIM))[i];
    ushort4 b1 = ((const ushort4*)(c1 + (size_t)p.y * C_DIM))[i];
    float4 r;
    r.x = w.x * (bf2f(a0.x) + bf2f(a1.x)) + w.y * (bf2f(b0.x) + bf2f(b1.x));
    r.y = w.x * (bf2f(a0.y) + bf2f(a1.y)) + w.y * (bf2f(b0.y) + bf2f(b1.y));
    r.z = w.x * (bf2f(a0.z) + bf2f(a1.z)) + w.y * (bf2f(b0.z) + bf2f(b1.z));
    r.w = w.x * (bf2f(a0.w) + bf2f(a1.w)) + w.y * (bf2f(b0.w) + bf2f(b1.w));
    ((float4*)(out + (size_t)t * C_DIM))[i] = r;
}

extern "C" void kernel_launch(void* const* d_in, const int* in_sizes, int n_in,
                              void* d_out, int out_size, void* d_ws, size_t ws_size,
                              hipStream_t stream) {
    (void)in_sizes; (void)n_in; (void)out_size; (void)ws_size;
    const float* x       = (const float*)d_in[0];
    const float* noise   = (const float*)d_in[1];
    const float* w_gate  = (const float*)d_in[2];
    const float* b_gate  = (const float*)d_in[3];
    const float* w_noise = (const float*)d_in[4];
    const float* b_noise = (const float*)d_in[5];
    const float* w1      = (const float*)d_in[6];
    const float* b1      = (const float*)d_in[7];
    const float* w2      = (const float*)d_in[8];
    const float* b2      = (const float*)d_in[9];
    float* out = (float*)d_out;

    char* w = (char*)d_ws;
    size_t off = 0;
    int* meta = (int*)(w + off); off += 256;
    int2* tok_e = (int2*)(w + off); off += (size_t)NTOK * 8;
    float2* tok_w = (float2*)(w + off); off += (size_t)NTOK * 8;
    int2* tok_pos = (int2*)(w + off); off += (size_t)NTOK * 8;
    int* rowtok = (int*)(w + off); off += (size_t)MAXROWS * 4;
    unsigned short* H = (unsigned short*)(w + off); off += (size_t)MAXROWS * DFF_DIM * 2;
    unsigned short* w2b = (unsigned short*)(w + off); off += (size_t)E_NUM * C_DIM * DFF_DIM * 2;
    unsigned short* c0 = (unsigned short*)(w + off); off += (size_t)MAXROWS * C_DIM * 2;
    unsigned short* c1 = (unsigned short*)(w + off); off += (size_t)MAXROWS * C_DIM * 2;
    unsigned short* xb = (unsigned short*)(w + off); off += (size_t)NTOK * C_DIM * 2;
    unsigned short* w1b = (unsigned short*)(w + off); off += (size_t)E_NUM * DFF_DIM * C_DIM * 2;

    hipMemsetAsync(meta, 0, 256, stream);

    fused_kernel<<<NB_RT + NB_T1 + NB_T2 + NTOK, 256, 17408, stream>>>(
        x, noise, w_gate, w_noise, b_gate, b_noise, meta, tok_e, tok_w, rowtok,
        w1, w1b, w2, w2b, xb);

    assign_kernel<<<NTOK / 256, 256, 0, stream>>>(meta, tok_e, tok_pos, rowtok);

    hipFuncSetAttribute((const void*)gemm8_kernel<C_DIM, C_DIM, DFF_DIM, 1, true>,
                        hipFuncAttributeMaxDynamicSharedMemorySize, 131072);
    gemm8_kernel<C_DIM, C_DIM, DFF_DIM, 1, true>
        <<<dim3((MAXROWS / 256) * (DFF_DIM / 256), 1, 1), 512, 131072, stream>>>(
            xb, w1b, b1, H, nullptr, nullptr, meta, rowtok);

    hipFuncSetAttribute((const void*)gemm8_kernel<DFF_DIM, DFF_DIM / 2, C_DIM, 2, false>,
                        hipFuncAttributeMaxDynamicSharedMemorySize, 131072);
    gemm8_kernel<DFF_DIM, DFF_DIM / 2, C_DIM, 2, false>
        <<<dim3((MAXROWS / 256) * (C_DIM / 256), 1, 2), 512, 131072, stream>>>(
            H, w2b, b2, nullptr, c0, c1, meta, nullptr);

    combine_kernel<<<NTOK, 256, 0, stream>>>(c0, c1, tok_pos, tok_w, out);
}